// Round 2
// baseline (93.094 us; speedup 1.0000x reference)
//
#include <hip/hip_runtime.h>
#include <math.h>

#define BATCH   4096
#define NN      22            // 1 self + 10 ally + 11 opp
#define D       64
#define NEG_BIG (-3.0e38f)

#define WAVES   8
#define NB      2
#define BPB     (WAVES * NB)      // 16 batches per block
#define GRID    (BATCH / BPB)     // 256 blocks = 1 per CU
#define THREADS (WAVES * 64)      // 512

// ---- dynamic-LDS float offsets ----
#define WT_OFF   0                 // W_T[3][64][68]  (W_T[t][hd][d])
#define WT_T     4352              // 64*68
#define UV_OFF   13056             // uv[12][68]: 0..8 = u[s*3+t], 9..11 = v[t]
#define UV_ROW   68
#define H_OFF    13872             // h tile per wave: [22][68]
#define H_WAVE   1496
#define H_ROW    68
#define G_OFF    25840             // g[wave][nb][3][64]
#define G_SEG    192
#define W_OFF    28912             // w scratch per wave: [3][24] (+pad)
#define W_SEG    96
#define LDS_FLOATS 29680
#define LDS_BYTES  (LDS_FLOATS * 4)   // 118720 B

__device__ __forceinline__ float wave_sum(float x) {
#pragma unroll
    for (int m = 32; m >= 1; m >>= 1) x += __shfl_xor(x, m, 64);
    return x;
}
__device__ __forceinline__ float wave_max(float x) {
#pragma unroll
    for (int m = 32; m >= 1; m >>= 1) x = fmaxf(x, __shfl_xor(x, m, 64));
    return x;
}
__device__ __forceinline__ float dot4(float4 p, float4 q) {
    return p.x * q.x + p.y * q.y + p.z * q.z + p.w * q.w;
}

__global__ __launch_bounds__(THREADS, 1)
void hetgat_kernel(const float* __restrict__ h,
                   const void* __restrict__ mask_raw,
                   const float* __restrict__ W,
                   const float* __restrict__ a,
                   float* __restrict__ out) {
    extern __shared__ float lds[];

    const int tid  = threadIdx.x;
    const int lane = tid & 63;
    const int wave = tid >> 6;

    // ======== preamble (block-wide, once) ========
    // A) stage W transposed: W_T[t][hd][d] = W[t][d][hd]
#pragma unroll
    for (int i = 0; i < 24; ++i) {
        int e  = i * 512 + tid;          // 0..12287
        int t  = e >> 12;
        int r  = e & 4095;
        int d  = r >> 6, hd = r & 63;
        lds[WT_OFF + t * WT_T + hd * 68 + d] = W[e];
    }
    // B) uv[vec][d]: vec<9 -> u[s*3+ta] = W[s]row_d . a[ta][:64]; vec>=9 -> v[t] = W[t]row_d . a[t][64:]
#pragma unroll
    for (int k = 0; k < 2; ++k) {
        int e = k * 512 + tid;
        if (e < 768) {
            int vec = e >> 6, d = e & 63;
            int s    = (vec < 9) ? (vec / 3) : (vec - 9);
            int aoff = (vec < 9) ? ((vec % 3) * 2 * D) : ((vec - 9) * 2 * D + D);
            const float4* wrow = (const float4*)(W + (size_t)s * 4096 + d * 64);
            const float4* arow = (const float4*)(a + aoff);
            float acc = 0.f;
#pragma unroll
            for (int i = 0; i < 16; ++i) acc += dot4(wrow[i], arow[i]);
            lds[UV_OFF + vec * UV_ROW + d] = acc;
        }
    }
    __syncthreads();

    // mask dtype autodetect (bool-bytes vs int32), wave-uniform.
    const unsigned char* mb = (const unsigned char*)mask_raw;
    const bool bytelayout = (__ballot(((lane & 3) != 0) && (mb[lane] != 0)) != 0ULL);

    float* hW    = lds + H_OFF + wave * H_WAVE;
    float* wwave = lds + W_OFF + wave * W_SEG;

    // lane -> (t, n) mapping for the z-dots
    int tq = lane / 21; if (tq > 2) tq = 2;      // 0..2
    int nn = lane - tq * 21 + 1;                 // 1..21 (lane63 -> 22, invalid)
    int row = (nn > 21) ? 21 : nn;
    const bool valid = (lane < 63);

#pragma unroll
    for (int nb = 0; nb < NB; ++nb) {
        const int b = blockIdx.x * BPB + wave * NB + nb;
        const float* hb = h + (size_t)b * NN * D;

        // ---- cooperative h load -> LDS tile (pad-68 rows) ----
#pragma unroll
        for (int k = 0; k < 6; ++k) {
            int f4 = k * 64 + lane;              // float4 index, 352 total
            if (f4 < 352) {
                float4 v = ((const float4*)hb)[f4];
                int f = f4 * 4;
                int n = f >> 6, c = f & 63;
                *(float4*)&hW[n * H_ROW + c] = v;
            }
        }
        __threadfence_block();   // order LDS writes vs cross-lane reads (single wave, lockstep)

        // ---- h rows lane=feature ----
        float hreg[NN];
#pragma unroll
        for (int n = 0; n < NN; ++n) hreg[n] = hW[n * H_ROW + lane];

        // ---- masks -> 3 wave-uniform 64-bit words ----
        unsigned long long mt[3];
        if (bytelayout) {
#pragma unroll
            for (int t = 0; t < 3; ++t)
                mt[t] = __ballot((lane < NN) && (mb[(size_t)t * BATCH * NN + (size_t)b * NN + lane] != 0));
        } else {
            const int* mi = (const int*)mask_raw;
#pragma unroll
            for (int t = 0; t < 3; ++t)
                mt[t] = __ballot((lane < NN) && (mi[(size_t)t * BATCH * NN + (size_t)b * NN + lane] != 0));
        }

        // ---- z dot: lane owns (tq, nn); z = h[nn] . v[tq] ----
        float zacc = 0.f;
        {
            const float4* hr = (const float4*)&hW[row * H_ROW];
            const float4* vr = (const float4*)&lds[UV_OFF + (9 + tq) * UV_ROW];
#pragma unroll
            for (int i = 0; i < 16; ++i) zacc += dot4(hr[i], vr[i]);
        }

        // ---- E dots: lanes 0..8 compute E[vec] = h0 . u[vec] ----
        float eacc = 0.f;
        if (lane < 9) {
            const float4* h0 = (const float4*)&hW[0];
            const float4* ur = (const float4*)&lds[UV_OFF + lane * UV_ROW];
#pragma unroll
            for (int i = 0; i < 16; ++i) eacc += dot4(h0[i], ur[i]);
        }
        // gather E[s*3+tq] for s=0..2 (ds_bpermute from lanes 0..8)
        float E0 = __shfl(eacc, 0 + tq, 64);
        float E1 = __shfl(eacc, 3 + tq, 64);
        float E2 = __shfl(eacc, 6 + tq, 64);
        float Em = fmaxf(fmaxf(E0, E1), E2);
        float Sv = __expf(E0 - Em) + __expf(E1 - Em) + __expf(E2 - Em);

        // ---- masked two-branch softmax (factored over s) ----
        float val = zacc + Em;
        bool  msk = (mt[tq] >> nn) & 1ull;       // true = exclude
        bool  fa  = valid && (nn <= 10) && !msk;
        bool  fo  = valid && (nn >= 11) && !msk;

        float Ma = wave_max(fa ? val : NEG_BIG);
        float Mo = wave_max(fo ? val : NEG_BIG);

        float ca = fa ? __expf(val - Ma) * Sv : 0.f;
        float co = fo ? __expf(val - Mo) * Sv : 0.f;
        float Da = wave_sum(ca);
        float Do = wave_sum(co);
        float rDa = (Da > 0.f) ? 1.0f / Da : 0.f;
        float rDo = (Do > 0.f) ? 1.0f / Do : 0.f;

        float w = fa ? ca * rDa : (fo ? co * rDo : 0.f);

        // publish w[t][n-1] (layout [3][24]; lane63 writes 0 to unused pad slot)
        wwave[tq * 24 + (nn - 1)] = w;
        __threadfence_block();

        // ---- g[t] = sum_n w[t,n]*h[n] + selfbit*h0   (lane = feature) ----
        float gt[3];
#pragma unroll
        for (int t = 0; t < 3; ++t) {
            gt[t] = ((mt[t] >> 0) & 1ull) ? hreg[0] : 0.f;
#pragma unroll
            for (int j = 0; j < 5; ++j) {        // n = 1..20 via float4
                float4 w4 = *(const float4*)&wwave[t * 24 + 4 * j];
                gt[t] += w4.x * hreg[1 + 4 * j] + w4.y * hreg[2 + 4 * j]
                       + w4.z * hreg[3 + 4 * j] + w4.w * hreg[4 + 4 * j];
            }
            gt[t] += wwave[t * 24 + 20] * hreg[21];   // n = 21 tail
        }

        // publish g for the projection pass (same wave reads it back)
        float* gW = lds + G_OFF + (wave * NB + nb) * G_SEG;
#pragma unroll
        for (int t = 0; t < 3; ++t) gW[t * 64 + lane] = gt[t];
    }
    __threadfence_block();

    // ======== projection: out[b][lane] = elu( sum_t g[t] . W_T[t][lane][:] ) ========
    float res[NB];
#pragma unroll
    for (int nb = 0; nb < NB; ++nb) res[nb] = 0.f;

    const float4* g0 = (const float4*)(lds + G_OFF + (wave * NB + 0) * G_SEG);
    const float4* g1 = (const float4*)(lds + G_OFF + (wave * NB + 1) * G_SEG);
#pragma unroll
    for (int t = 0; t < 3; ++t) {
        const float4* wr = (const float4*)&lds[WT_OFF + t * WT_T + lane * 68];
#pragma unroll
        for (int i = 0; i < 16; ++i) {
            float4 wv  = wr[i];                  // W_T[t][lane][4i..4i+3]
            float4 ga4 = g0[t * 16 + i];         // broadcast
            float4 gb4 = g1[t * 16 + i];
            res[0] += dot4(ga4, wv);
            res[1] += dot4(gb4, wv);
        }
    }

#pragma unroll
    for (int nb = 0; nb < NB; ++nb) {
        const int b = blockIdx.x * BPB + wave * NB + nb;
        float x = res[nb];
        float y = (x > 0.f) ? x : (__expf(x) - 1.0f);
        out[(size_t)b * D + lane] = y;
    }
}

extern "C" void kernel_launch(void* const* d_in, const int* in_sizes, int n_in,
                              void* d_out, int out_size, void* d_ws, size_t ws_size,
                              hipStream_t stream) {
    const float* h    = (const float*)d_in[0];
    // d_in[1] = num_ally (10), d_in[2] = num_opp (11): compile-time constants here
    const void*  mask = d_in[3];
    const float* W    = (const float*)d_in[4];
    const float* a    = (const float*)d_in[5];
    float*       out  = (float*)d_out;

    hipFuncSetAttribute((const void*)hetgat_kernel,
                        hipFuncAttributeMaxDynamicSharedMemorySize, LDS_BYTES);
    hetgat_kernel<<<GRID, THREADS, LDS_BYTES, stream>>>(h, mask, W, a, out);
}